// Round 5
// baseline (592.947 us; speedup 1.0000x reference)
//
#include <hip/hip_runtime.h>
#include <stdint.h>

#define DI __device__ __forceinline__

typedef __attribute__((ext_vector_type(8))) __bf16 bf16x8;
typedef __attribute__((ext_vector_type(8))) short short8;
typedef __attribute__((ext_vector_type(4))) float f32x4;
typedef __attribute__((ext_vector_type(16))) float f32x16;

DI unsigned short f2bf(float f) {
    union { float f; uint32_t u; } v; v.f = f;
    uint32_t r = v.u + 0x7FFFu + ((v.u >> 16) & 1u);   // RNE
    return (unsigned short)(r >> 16);
}
DI uint32_t pk2(float a, float b) {        // {lo=bf16(a), hi=bf16(b)} in 1 instr
    uint32_t r;
    asm("v_cvt_pk_bf16_f32 %0, %1, %2" : "=v"(r) : "v"(a), "v"(b));
    return r;
}
DI bf16x8 asb(short8 s) { union { short8 s; bf16x8 b; } u; u.s = s; return u.b; }
DI bf16x8 asb4(uint32_t a, uint32_t b, uint32_t c, uint32_t d) {
    union { uint32_t u[4]; bf16x8 b; } x; x.u[0] = a; x.u[1] = b; x.u[2] = c; x.u[3] = d; return x.b;
}
DI void gload16(const void* g, void* l) {
    __builtin_amdgcn_global_load_lds(
        (const __attribute__((address_space(1))) void*)g,
        (__attribute__((address_space(3))) void*)l, 16, 0, 0);
}
DI int swzc(int c) { return c ^ ((c >> 3) & 7); }   // XOR chunk swizzle within a row

// ------------- fused prep: cast x/Wqkv/Wout to bf16 + RoPE table -----------
__global__ __launch_bounds__(256) void prepk(
    const float* __restrict__ x, const float* __restrict__ Wqkv,
    const float* __restrict__ Wout,
    unsigned short* __restrict__ xb, unsigned short* __restrict__ wqkvb,
    unsigned short* __restrict__ woutb,
    float* __restrict__ cosT, float* __restrict__ sinT) {
    const int bid = blockIdx.x, tid = threadIdx.x;
    if (bid < 8192) {
        const float* in; unsigned short* out; int i;
        if (bid < 4096)      { in = x;    out = xb;    i = bid * 256 + tid; }
        else if (bid < 7168) { in = Wqkv; out = wqkvb; i = (bid - 4096) * 256 + tid; }
        else                 { in = Wout; out = woutb; i = (bid - 7168) * 256 + tid; }
        float4 v = ((const float4*)in)[i];
        union { unsigned short u[4]; uint2 q; } p;
        p.u[0] = f2bf(v.x); p.u[1] = f2bf(v.y); p.u[2] = f2bf(v.z); p.u[3] = f2bf(v.w);
        ((uint2*)out)[i] = p.q;
    } else {
        int i = (bid - 8192) * 256 + tid;       // 65536 total
        int n = i >> 5, d = i & 31;
        float inv = powf(10000.0f, -(float)(2 * d) * (1.0f / 64.0f));
        float a = (float)n * inv;
        float s, c;
        sincosf(a, &s, &c);
        cosT[i] = c; sinT[i] = s;
    }
}

// ---------------------- GEMM C = A * Bt^T  (bf16 MFMA) ---------------------
// Tile BM x 128, 4 waves (2x2), BK=32, 16x16x32 bf16 MFMA (m97 shape, R1-proven).
// MODE 0 (BM=128): qkv epilogue (RoPE; Q scaled by log2e/8; V transposed via
//                  LDS with key-permuted layout: slot s holds key swap23(s))
// MODE 1 (BM=64):  out epilogue (+bias, fp32 store)
template <int MODE, int BM>
__global__ __launch_bounds__(256) void gemm_bt(
    const unsigned short* __restrict__ A, const unsigned short* __restrict__ Bt,
    int M, int N, int K,
    unsigned short* __restrict__ Qbuf, unsigned short* __restrict__ Kbuf,
    unsigned short* __restrict__ Vt,
    const float* __restrict__ cosT, const float* __restrict__ sinT,
    float* __restrict__ Cout, const float* __restrict__ bias) {
    constexpr int WM = BM / 2;       // rows per wave
    constexpr int MI = WM / 16;      // A-frag count per wave
    __shared__ __align__(16) unsigned short As[BM * 32];
    __shared__ __align__(16) unsigned short Bs[128 * 32];
    const int tid = threadIdx.x;
    const int wave = tid >> 6, lane = tid & 63, g = lane >> 4, li = lane & 15;
    const int wr = wave >> 1, wc = wave & 1;
    const int m0 = blockIdx.y * BM, n0 = blockIdx.x * 128;

    f32x4 acc[MI][4] = {};
    const int nK = K >> 5;
    for (int kk = 0; kk < nK; ++kk) {
#pragma unroll
        for (int i = 0; i < BM / 64; ++i) {     // A tile: BM*4 chunks of 16B
            int cb = i * 256 + wave * 64;
            int c = cb + lane;
            int r = c >> 2, k0 = (c & 3) * 8;
            gload16(A + (size_t)(m0 + r) * K + kk * 32 + k0, &As[cb * 8]);
        }
#pragma unroll
        for (int i = 0; i < 2; ++i) {           // B tile: 512 chunks
            int cb = i * 256 + wave * 64;
            int c = cb + lane;
            int r = c >> 2, k0 = (c & 3) * 8;
            gload16(Bt + (size_t)(n0 + r) * K + kk * 32 + k0, &Bs[cb * 8]);
        }
        __syncthreads();
        short8 af[MI], bf[4];
#pragma unroll
        for (int mi = 0; mi < MI; ++mi)
            af[mi] = *(const short8*)&As[(wr * WM + mi * 16 + li) * 32 + g * 8];
#pragma unroll
        for (int ni = 0; ni < 4; ++ni)
            bf[ni] = *(const short8*)&Bs[(wc * 64 + ni * 16 + li) * 32 + g * 8];
#pragma unroll
        for (int mi = 0; mi < MI; ++mi)
#pragma unroll
            for (int ni = 0; ni < 4; ++ni)
                acc[mi][ni] = __builtin_amdgcn_mfma_f32_16x16x32_bf16(
                    asb(af[mi]), asb(bf[ni]), acc[mi][ni], 0, 0, 0);
        __syncthreads();
    }

    if (MODE == 1) {
#pragma unroll
        for (int mi = 0; mi < MI; ++mi) {
            int row = m0 + wr * WM + mi * 16 + 4 * g;
#pragma unroll
            for (int ni = 0; ni < 4; ++ni) {
                int col = n0 + wc * 64 + ni * 16 + li;
                float b = bias[col];
#pragma unroll
                for (int r = 0; r < 4; ++r)
                    Cout[(size_t)(row + r) * N + col] = acc[mi][ni][r] + b;
            }
        }
    } else {
        // three = fb/1024 is block-uniform; hh differs per wave-column
        const int fb = n0 + wc * 64;
        const int three = fb >> 10;
        const int hh = (fb & 1023) >> 6;
        const int bq = m0 >> 11;
        const int nb0 = m0 & 2047;
        const size_t bh = (size_t)(bq * 16 + hh);
        if (three < 2) {
            // Q/K with RoPE; Q scaled by log2e/8 (base-2 softmax fold)
#pragma unroll
            for (int mi = 0; mi < MI; ++mi) {
#pragma unroll
                for (int r = 0; r < 4; ++r) {
                    int n = nb0 + wr * WM + mi * 16 + 4 * g + r;
                    float v0 = acc[mi][0][r], v1 = acc[mi][1][r];
                    float v2 = acc[mi][2][r], v3 = acc[mi][3][r];
                    float c0 = cosT[n * 32 + li],      s0 = sinT[n * 32 + li];
                    float c1 = cosT[n * 32 + 16 + li], s1 = sinT[n * 32 + 16 + li];
                    float o0 = v0 * c0 - v2 * s0;
                    float o2 = v2 * c0 + v0 * s0;
                    float o1 = v1 * c1 - v3 * s1;
                    float o3 = v3 * c1 + v1 * s1;
                    if (three == 0) {
                        const float qs = 0.18033688f;  // 0.125 * log2(e)
                        o0 *= qs; o1 *= qs; o2 *= qs; o3 *= qs;
                    }
                    unsigned short* dst = (three == 0 ? Qbuf : Kbuf) + (bh * 2048 + n) * 64;
                    dst[li] = f2bf(o0); dst[16 + li] = f2bf(o1);
                    dst[32 + li] = f2bf(o2); dst[48 + li] = f2bf(o3);
                }
            }
        } else {
            // V: per-wave transpose via LDS (reuse As), with key-permutation
            // swap23 within each 16-token group (PV sigma-layout, see attnk)
            unsigned short* vtw = As + wave * 1024;        // [64 d][16 slots]
            const int gsw = ((g & 1) << 1) | (g >> 1);     // swap 2-bit halves
#pragma unroll
            for (int mi = 0; mi < MI; ++mi) {
                __syncthreads();               // prev-mi reads fully done
#pragma unroll
                for (int ni = 0; ni < 4; ++ni)
#pragma unroll
                    for (int r = 0; r < 4; ++r)
                        vtw[(ni * 16 + li) * 16 + 4 * gsw + r] = f2bf(acc[mi][ni][r]);
                __syncthreads();               // transpose writes visible
                uint4 lo = *(const uint4*)&vtw[lane * 16];
                uint4 hi = *(const uint4*)&vtw[lane * 16 + 8];
                int nbase = nb0 + wr * WM + mi * 16;
                unsigned short* dst = Vt + (bh * 64 + lane) * 2048 + nbase;
                *(uint4*)dst = lo;
                *(uint4*)(dst + 8) = hi;
            }
        }
    }
}

// ------------------------------ attention ---------------------------------
// 32x32x16 MFMA, swapped QK^T (S^T = K*Q^T): each lane owns one q-row.
// FIXED-BASE softmax: p = exp2(s) directly (s bounded; no online max, no
// rescale, lane-local l). Pipeline: write(kt+1) | barrier | issue(kt+2) |
// QK^T(kt+1) | exp/pack/PV(kt). Triple-buffered LDS so the single barrier
// protects both visibility and WAR (prev occupant's readers are 2 iters old).
__global__ __launch_bounds__(256) void attnk(
    const unsigned short* __restrict__ Qb, const unsigned short* __restrict__ Kb,
    const unsigned short* __restrict__ Vt, unsigned short* __restrict__ Obuf) {
    __shared__ __align__(16) unsigned short Ks[3][64 * 64];
    __shared__ __align__(16) unsigned short Vs[3][64 * 64];
    const int tid = threadIdx.x, wave = tid >> 6, lane = tid & 63;
    const int h = lane >> 5, li = lane & 31;

    // XCD-bijective swizzle: 512 blocks / 8 XCDs
    const int fid = blockIdx.y * 16 + blockIdx.x;
    const int logical = (fid & 7) * 64 + (fid >> 3);
    const int bh = logical >> 4, qt = logical & 15;
    const int q0 = qt * 128 + wave * 32;

    // Q B-frags: lane holds Q[q0+li][16c + 8h + j]  (pre-scaled by log2e/8)
    bf16x8 qf[4];
    const unsigned short* qp = Qb + ((size_t)bh * 2048 + q0 + li) * 64;
#pragma unroll
    for (int c = 0; c < 4; ++c) qf[c] = asb(*(const short8*)(qp + c * 16 + h * 8));

    // staging geometry: chunk c in [0,512): row=c>>3, cc=c&7
    const uint4* kg = (const uint4*)(Kb + (size_t)bh * 2048 * 64);
    const uint4* vg = (const uint4*)Vt;
    const int r0 = tid >> 3, r1 = (tid + 256) >> 3, cc = tid & 7;
    const int sw0 = swzc(tid) * 8, sw1 = swzc(tid + 256) * 8;
    const size_t vrow0 = ((size_t)bh * 64 + r0) * 256 + cc;
    const size_t vrow1 = ((size_t)bh * 64 + r1) * 256 + cc;

    uint4 kr0, kr1, vr0, vr1;
    auto issue_loads = [&](int nt) {
        kr0 = kg[nt * 512 + tid]; kr1 = kg[nt * 512 + 256 + tid];
        vr0 = vg[vrow0 + nt * 8]; vr1 = vg[vrow1 + nt * 8];
    };
    auto stage_write = [&](int b) {
        *(uint4*)&Ks[b][sw0] = kr0; *(uint4*)&Ks[b][sw1] = kr1;
        *(uint4*)&Vs[b][sw0] = vr0; *(uint4*)&Vs[b][sw1] = vr1;
    };

    f32x16 o0 = {}, o1 = {};
    float l_ = 0.f;

    auto qkt = [&](int b, f32x16& t0, f32x16& t1) {
        t0 = (f32x16){}; t1 = (f32x16){};
#pragma unroll
        for (int c = 0; c < 4; ++c) {
            int ch = 2 * c + h;
            bf16x8 k0 = asb(*(const short8*)&Ks[b][li * 64 + ((ch ^ (li & 7)) * 8)]);
            bf16x8 k1 = asb(*(const short8*)&Ks[b][(32 + li) * 64 + ((ch ^ (li & 7)) * 8)]);
            t0 = __builtin_amdgcn_mfma_f32_32x32x16_bf16(k0, qf[c], t0, 0, 0, 0);
            t1 = __builtin_amdgcn_mfma_f32_32x32x16_bf16(k1, qf[c], t1, 0, 0, 0);
        }
    };
    auto sfpv = [&](int b, f32x16& s0, f32x16& s1) {
        float sm0 = 0.f, sm1 = 0.f, sm2 = 0.f, sm3 = 0.f;
#pragma unroll
        for (int r = 0; r < 16; r += 2) {
            float a0 = __builtin_exp2f(s0[r]);     s0[r] = a0;     sm0 += a0;
            float a1 = __builtin_exp2f(s0[r + 1]); s0[r + 1] = a1; sm1 += a1;
            float b0 = __builtin_exp2f(s1[r]);     s1[r] = b0;     sm2 += b0;
            float b1 = __builtin_exp2f(s1[r + 1]); s1[r + 1] = b1; sm3 += b1;
        }
        l_ += (sm0 + sm1) + (sm2 + sm3);
        uint32_t w0[8], w1[8];
#pragma unroll
        for (int m = 0; m < 8; ++m) {
            w0[m] = pk2(s0[2 * m], s0[2 * m + 1]);
            w1[m] = pk2(s1[2 * m], s1[2 * m + 1]);
        }
#pragma unroll
        for (int ks = 0; ks < 4; ++ks) {
            const uint32_t* wk = (ks < 2) ? w0 : w1;
            const int sub = (ks & 1) * 4;
            bf16x8 pf = asb4(wk[sub], wk[sub + 1], wk[sub + 2], wk[sub + 3]);
            int ch = 2 * ks + h;
            bf16x8 vf0 = asb(*(const short8*)&Vs[b][li * 64 + ((ch ^ (li & 7)) * 8)]);
            bf16x8 vf1 = asb(*(const short8*)&Vs[b][(32 + li) * 64 + ((ch ^ (li & 7)) * 8)]);
            o0 = __builtin_amdgcn_mfma_f32_32x32x16_bf16(pf, vf0, o0, 0, 0, 0);
            o1 = __builtin_amdgcn_mfma_f32_32x32x16_bf16(pf, vf1, o1, 0, 0, 0);
        }
    };

    f32x16 sA0, sA1, sB0, sB1;

    // prologue: tile 0 staged, tile 1 in regs, QK^T(0) in flight
    issue_loads(0);
    stage_write(0);
    __syncthreads();
    issue_loads(1);
    qkt(0, sA0, sA1);

#pragma unroll
    for (int kt = 0; kt < 32; ++kt) {
        if (kt < 31) {
            stage_write((kt + 1) % 3);
            __syncthreads();
            if (kt < 30) issue_loads(kt + 2);
            if ((kt & 1) == 0) qkt((kt + 1) % 3, sB0, sB1);
            else               qkt((kt + 1) % 3, sA0, sA1);
        }
        if ((kt & 1) == 0) sfpv(kt % 3, sA0, sA1);
        else               sfpv(kt % 3, sB0, sB1);
    }

    // epilogue: combine lane-partial l across the two half-lanes, normalize
    float lfull = l_ + __shfl_xor(l_, 32);
    float linv = 1.0f / lfull;
    const int b = bh >> 4, hh = bh & 15;
#pragma unroll
    for (int r = 0; r < 16; ++r) {
        int qrow = (r & 3) + 8 * (r >> 2) + 4 * h;
        float lr = __shfl(linv, qrow);
        int n = q0 + qrow;
        unsigned short* dst = Obuf + ((size_t)(b * 2048 + n)) * 1024 + hh * 64 + li;
        dst[0]  = f2bf(o0[r] * lr);
        dst[32] = f2bf(o1[r] * lr);
    }
}

// ------------------------------- launch ------------------------------------
extern "C" void kernel_launch(void* const* d_in, const int* in_sizes, int n_in,
                              void* d_out, int out_size, void* d_ws, size_t ws_size,
                              hipStream_t stream) {
    const float* x    = (const float*)d_in[0];
    const float* Wqkv = (const float*)d_in[1];
    const float* Wout = (const float*)d_in[2];
    const float* bout = (const float*)d_in[3];
    float* out = (float*)d_out;
    char* ws = (char*)d_ws;

    size_t off = 0;
    unsigned short* xb    = (unsigned short*)(ws + off);
    unsigned short* Obuf  = xb;                                      // alias
    off += (size_t)4096 * 1024 * 2;
    unsigned short* wqkvb = (unsigned short*)(ws + off); off += (size_t)3072 * 1024 * 2;
    unsigned short* woutb = (unsigned short*)(ws + off); off += (size_t)1024 * 1024 * 2;
    float* cosT = (float*)(ws + off); off += (size_t)2048 * 32 * 4;
    float* sinT = (float*)(ws + off); off += (size_t)2048 * 32 * 4;
    unsigned short* Qbuf = (unsigned short*)(ws + off); off += (size_t)32 * 2048 * 64 * 2;
    unsigned short* Kbuf = (unsigned short*)(ws + off); off += (size_t)32 * 2048 * 64 * 2;
    unsigned short* Vt   = (unsigned short*)(ws + off); off += (size_t)32 * 64 * 2048 * 2;

    prepk<<<8448, 256, 0, stream>>>(x, Wqkv, Wout, xb, wqkvb, woutb, cosT, sinT);

    gemm_bt<0, 128><<<dim3(24, 32), 256, 0, stream>>>(
        xb, wqkvb, 4096, 3072, 1024, Qbuf, Kbuf, Vt, cosT, sinT, nullptr, nullptr);

    attnk<<<dim3(16, 32), 256, 0, stream>>>(Qbuf, Kbuf, Vt, Obuf);

    gemm_bt<1, 64><<<dim3(8, 64), 256, 0, stream>>>(
        Obuf, woutb, 4096, 1024, 1024, nullptr, nullptr, nullptr, nullptr, nullptr,
        out, bout);
}

// Round 6
// 205.685 us; speedup vs baseline: 2.8828x; 2.8828x over previous
//
#include <hip/hip_runtime.h>
#include <stdint.h>

#define DI __device__ __forceinline__

typedef __attribute__((ext_vector_type(8))) __bf16 bf16x8;
typedef __attribute__((ext_vector_type(8))) short short8;
typedef __attribute__((ext_vector_type(4))) float f32x4;
typedef __attribute__((ext_vector_type(16))) float f32x16;

DI unsigned short f2bf(float f) {
    union { float f; uint32_t u; } v; v.f = f;
    uint32_t r = v.u + 0x7FFFu + ((v.u >> 16) & 1u);   // RNE
    return (unsigned short)(r >> 16);
}
DI uint32_t pk2(float a, float b) {        // {lo=bf16(a), hi=bf16(b)} in 1 instr
    uint32_t r;
    asm("v_cvt_pk_bf16_f32 %0, %1, %2" : "=v"(r) : "v"(a), "v"(b));
    return r;
}
DI bf16x8 asb(short8 s) { union { short8 s; bf16x8 b; } u; u.s = s; return u.b; }
DI bf16x8 asb4(uint32_t a, uint32_t b, uint32_t c, uint32_t d) {
    union { uint32_t u[4]; bf16x8 b; } x; x.u[0] = a; x.u[1] = b; x.u[2] = c; x.u[3] = d; return x.b;
}
DI void gload16(const void* g, void* l) {
    __builtin_amdgcn_global_load_lds(
        (const __attribute__((address_space(1))) void*)g,
        (__attribute__((address_space(3))) void*)l, 16, 0, 0);
}
DI int swzc(int c) { return c ^ ((c >> 3) & 7); }   // XOR chunk swizzle within a row

// ------------- fused prep: cast x/Wqkv/Wout to bf16 + RoPE table -----------
__global__ __launch_bounds__(256) void prepk(
    const float* __restrict__ x, const float* __restrict__ Wqkv,
    const float* __restrict__ Wout,
    unsigned short* __restrict__ xb, unsigned short* __restrict__ wqkvb,
    unsigned short* __restrict__ woutb,
    float* __restrict__ cosT, float* __restrict__ sinT) {
    const int bid = blockIdx.x, tid = threadIdx.x;
    if (bid < 8192) {
        const float* in; unsigned short* out; int i;
        if (bid < 4096)      { in = x;    out = xb;    i = bid * 256 + tid; }
        else if (bid < 7168) { in = Wqkv; out = wqkvb; i = (bid - 4096) * 256 + tid; }
        else                 { in = Wout; out = woutb; i = (bid - 7168) * 256 + tid; }
        float4 v = ((const float4*)in)[i];
        union { unsigned short u[4]; uint2 q; } p;
        p.u[0] = f2bf(v.x); p.u[1] = f2bf(v.y); p.u[2] = f2bf(v.z); p.u[3] = f2bf(v.w);
        ((uint2*)out)[i] = p.q;
    } else {
        int i = (bid - 8192) * 256 + tid;       // 65536 total
        int n = i >> 5, d = i & 31;
        float inv = powf(10000.0f, -(float)(2 * d) * (1.0f / 64.0f));
        float a = (float)n * inv;
        float s, c;
        sincosf(a, &s, &c);
        cosT[i] = c; sinT[i] = s;
    }
}

// ---------------------- GEMM C = A * Bt^T  (bf16 MFMA) ---------------------
// Tile BM x 128, 4 waves (2x2), BK=32, 16x16x32 bf16 MFMA (m97 shape, R1-proven).
// MODE 0 (BM=128): qkv epilogue (RoPE; Q scaled by log2e/8; V transposed via
//                  LDS with key-permuted layout: slot s holds key swap23(s))
// MODE 1 (BM=64):  out epilogue (+bias, fp32 store)
template <int MODE, int BM>
__global__ __launch_bounds__(256) void gemm_bt(
    const unsigned short* __restrict__ A, const unsigned short* __restrict__ Bt,
    int M, int N, int K,
    unsigned short* __restrict__ Qbuf, unsigned short* __restrict__ Kbuf,
    unsigned short* __restrict__ Vt,
    const float* __restrict__ cosT, const float* __restrict__ sinT,
    float* __restrict__ Cout, const float* __restrict__ bias) {
    constexpr int WM = BM / 2;       // rows per wave
    constexpr int MI = WM / 16;      // A-frag count per wave
    __shared__ __align__(16) unsigned short As[BM * 32];
    __shared__ __align__(16) unsigned short Bs[128 * 32];
    const int tid = threadIdx.x;
    const int wave = tid >> 6, lane = tid & 63, g = lane >> 4, li = lane & 15;
    const int wr = wave >> 1, wc = wave & 1;
    const int m0 = blockIdx.y * BM, n0 = blockIdx.x * 128;

    f32x4 acc[MI][4] = {};
    const int nK = K >> 5;
    for (int kk = 0; kk < nK; ++kk) {
#pragma unroll
        for (int i = 0; i < BM / 64; ++i) {     // A tile: BM*4 chunks of 16B
            int cb = i * 256 + wave * 64;
            int c = cb + lane;
            int r = c >> 2, k0 = (c & 3) * 8;
            gload16(A + (size_t)(m0 + r) * K + kk * 32 + k0, &As[cb * 8]);
        }
#pragma unroll
        for (int i = 0; i < 2; ++i) {           // B tile: 512 chunks
            int cb = i * 256 + wave * 64;
            int c = cb + lane;
            int r = c >> 2, k0 = (c & 3) * 8;
            gload16(Bt + (size_t)(n0 + r) * K + kk * 32 + k0, &Bs[cb * 8]);
        }
        __syncthreads();
        short8 af[MI], bf[4];
#pragma unroll
        for (int mi = 0; mi < MI; ++mi)
            af[mi] = *(const short8*)&As[(wr * WM + mi * 16 + li) * 32 + g * 8];
#pragma unroll
        for (int ni = 0; ni < 4; ++ni)
            bf[ni] = *(const short8*)&Bs[(wc * 64 + ni * 16 + li) * 32 + g * 8];
#pragma unroll
        for (int mi = 0; mi < MI; ++mi)
#pragma unroll
            for (int ni = 0; ni < 4; ++ni)
                acc[mi][ni] = __builtin_amdgcn_mfma_f32_16x16x32_bf16(
                    asb(af[mi]), asb(bf[ni]), acc[mi][ni], 0, 0, 0);
        __syncthreads();
    }

    if (MODE == 1) {
#pragma unroll
        for (int mi = 0; mi < MI; ++mi) {
            int row = m0 + wr * WM + mi * 16 + 4 * g;
#pragma unroll
            for (int ni = 0; ni < 4; ++ni) {
                int col = n0 + wc * 64 + ni * 16 + li;
                float b = bias[col];
#pragma unroll
                for (int r = 0; r < 4; ++r)
                    Cout[(size_t)(row + r) * N + col] = acc[mi][ni][r] + b;
            }
        }
    } else {
        // three = fb/1024 is block-uniform; hh differs per wave-column
        const int fb = n0 + wc * 64;
        const int three = fb >> 10;
        const int hh = (fb & 1023) >> 6;
        const int bq = m0 >> 11;
        const int nb0 = m0 & 2047;
        const size_t bh = (size_t)(bq * 16 + hh);
        if (three < 2) {
            // Q/K with RoPE; Q scaled by log2e/8 (base-2 softmax fold)
#pragma unroll
            for (int mi = 0; mi < MI; ++mi) {
#pragma unroll
                for (int r = 0; r < 4; ++r) {
                    int n = nb0 + wr * WM + mi * 16 + 4 * g + r;
                    float v0 = acc[mi][0][r], v1 = acc[mi][1][r];
                    float v2 = acc[mi][2][r], v3 = acc[mi][3][r];
                    float c0 = cosT[n * 32 + li],      s0 = sinT[n * 32 + li];
                    float c1 = cosT[n * 32 + 16 + li], s1 = sinT[n * 32 + 16 + li];
                    float o0 = v0 * c0 - v2 * s0;
                    float o2 = v2 * c0 + v0 * s0;
                    float o1 = v1 * c1 - v3 * s1;
                    float o3 = v3 * c1 + v1 * s1;
                    if (three == 0) {
                        const float qs = 0.18033688f;  // 0.125 * log2(e)
                        o0 *= qs; o1 *= qs; o2 *= qs; o3 *= qs;
                    }
                    unsigned short* dst = (three == 0 ? Qbuf : Kbuf) + (bh * 2048 + n) * 64;
                    dst[li] = f2bf(o0); dst[16 + li] = f2bf(o1);
                    dst[32 + li] = f2bf(o2); dst[48 + li] = f2bf(o3);
                }
            }
        } else {
            // V: per-wave transpose via LDS (reuse As), with key-permutation
            // swap23 within each 16-token group (PV sigma-layout, see attnk)
            unsigned short* vtw = As + wave * 1024;        // [64 d][16 slots]
            const int gsw = ((g & 1) << 1) | (g >> 1);     // swap 2-bit halves
#pragma unroll
            for (int mi = 0; mi < MI; ++mi) {
                __syncthreads();               // prev-mi reads fully done
#pragma unroll
                for (int ni = 0; ni < 4; ++ni)
#pragma unroll
                    for (int r = 0; r < 4; ++r)
                        vtw[(ni * 16 + li) * 16 + 4 * gsw + r] = f2bf(acc[mi][ni][r]);
                __syncthreads();               // transpose writes visible
                uint4 lo = *(const uint4*)&vtw[lane * 16];
                uint4 hi = *(const uint4*)&vtw[lane * 16 + 8];
                int nbase = nb0 + wr * WM + mi * 16;
                unsigned short* dst = Vt + (bh * 64 + lane) * 2048 + nbase;
                *(uint4*)dst = lo;
                *(uint4*)(dst + 8) = hi;
            }
        }
    }
}

// ------------------------------ attention ---------------------------------
// 32x32x16 MFMA, swapped QK^T (S^T = K*Q^T): each lane owns one q-row.
// FIXED-BASE softmax: p = exp2(s) directly (s bounded), lane-local l.
// Double-buffered LDS; loads for tile kt+1 issued AFTER the barrier so they
// fly under tile kt's compute (the pre-barrier vmcnt drain was R4's stall).
__global__ __launch_bounds__(256) void attnk(
    const unsigned short* __restrict__ Qb, const unsigned short* __restrict__ Kb,
    const unsigned short* __restrict__ Vt, unsigned short* __restrict__ Obuf) {
    __shared__ __align__(16) unsigned short Ks[2][64 * 64];
    __shared__ __align__(16) unsigned short Vs[2][64 * 64];
    const int tid = threadIdx.x, wave = tid >> 6, lane = tid & 63;
    const int h = lane >> 5, li = lane & 31;

    // XCD-bijective swizzle: 512 blocks / 8 XCDs
    const int fid = blockIdx.y * 16 + blockIdx.x;
    const int logical = (fid & 7) * 64 + (fid >> 3);
    const int bh = logical >> 4, qt = logical & 15;
    const int q0 = qt * 128 + wave * 32;

    // Q B-frags: lane holds Q[q0+li][16c + 8h + j]  (pre-scaled by log2e/8)
    bf16x8 qf[4];
    const unsigned short* qp = Qb + ((size_t)bh * 2048 + q0 + li) * 64;
#pragma unroll
    for (int c = 0; c < 4; ++c) qf[c] = asb(*(const short8*)(qp + c * 16 + h * 8));

    // staging geometry: chunk c in [0,512): row=c>>3, cc=c&7
    const uint4* kg = (const uint4*)(Kb + (size_t)bh * 2048 * 64);
    const uint4* vg = (const uint4*)Vt;
    const int r0 = tid >> 3, r1 = (tid + 256) >> 3, cc = tid & 7;
    const int sw0 = swzc(tid) * 8, sw1 = swzc(tid + 256) * 8;
    const size_t vrow0 = ((size_t)bh * 64 + r0) * 256 + cc;
    const size_t vrow1 = ((size_t)bh * 64 + r1) * 256 + cc;

    uint4 kr0, kr1, vr0, vr1;

    f32x16 o0 = {}, o1 = {};
    float l_ = 0.f;

    // prologue: load+stage tile 0; after barrier, issue loads for tile 1
    kr0 = kg[tid]; kr1 = kg[256 + tid];
    vr0 = vg[vrow0]; vr1 = vg[vrow1];
    *(uint4*)&Ks[0][sw0] = kr0; *(uint4*)&Ks[0][sw1] = kr1;
    *(uint4*)&Vs[0][sw0] = vr0; *(uint4*)&Vs[0][sw1] = vr1;
    __syncthreads();
    kr0 = kg[512 + tid]; kr1 = kg[512 + 256 + tid];
    vr0 = vg[vrow0 + 8]; vr1 = vg[vrow1 + 8];

    for (int kt = 0; kt < 32; ++kt) {
        const int cur = kt & 1;

        // S^T = K Q^T : col=li=q, row=(r&3)+8*(r>>2)+4h = key
        f32x16 s0 = {}, s1 = {};
#pragma unroll
        for (int c = 0; c < 4; ++c) {
            int ch = 2 * c + h;
            bf16x8 k0 = asb(*(const short8*)&Ks[cur][li * 64 + ((ch ^ (li & 7)) * 8)]);
            bf16x8 k1 = asb(*(const short8*)&Ks[cur][(32 + li) * 64 + ((ch ^ (li & 7)) * 8)]);
            s0 = __builtin_amdgcn_mfma_f32_32x32x16_bf16(k0, qf[c], s0, 0, 0, 0);
            s1 = __builtin_amdgcn_mfma_f32_32x32x16_bf16(k1, qf[c], s1, 0, 0, 0);
        }

        // fixed-base softmax: p = exp2(s); lane-local partial sum
        float sm0 = 0.f, sm1 = 0.f;
#pragma unroll
        for (int r = 0; r < 16; ++r) {
            float p0 = __builtin_exp2f(s0[r]); s0[r] = p0; sm0 += p0;
            float p1 = __builtin_exp2f(s1[r]); s1[r] = p1; sm1 += p1;
        }
        l_ += sm0 + sm1;

        // pack P to bf16 words (v_cvt_pk_bf16_f32)
        uint32_t w0[8], w1[8];
#pragma unroll
        for (int m = 0; m < 8; ++m) {
            w0[m] = pk2(s0[2 * m], s0[2 * m + 1]);
            w1[m] = pk2(s1[2 * m], s1[2 * m + 1]);
        }

        // PV: O += P V. sigma-permuted V makes lane's own words the A-frag.
#pragma unroll
        for (int ks = 0; ks < 4; ++ks) {
            const uint32_t* wk = (ks < 2) ? w0 : w1;
            const int sub = (ks & 1) * 4;
            bf16x8 pf = asb4(wk[sub], wk[sub + 1], wk[sub + 2], wk[sub + 3]);
            int ch = 2 * ks + h;
            bf16x8 vf0 = asb(*(const short8*)&Vs[cur][li * 64 + ((ch ^ (li & 7)) * 8)]);
            bf16x8 vf1 = asb(*(const short8*)&Vs[cur][(32 + li) * 64 + ((ch ^ (li & 7)) * 8)]);
            o0 = __builtin_amdgcn_mfma_f32_32x32x16_bf16(pf, vf0, o0, 0, 0, 0);
            o1 = __builtin_amdgcn_mfma_f32_32x32x16_bf16(pf, vf1, o1, 0, 0, 0);
        }

        if (kt < 31) {
            // stage tile kt+1 (regs loaded during THIS tile's compute)
            const int nxt = cur ^ 1;
            *(uint4*)&Ks[nxt][sw0] = kr0; *(uint4*)&Ks[nxt][sw1] = kr1;
            *(uint4*)&Vs[nxt][sw0] = vr0; *(uint4*)&Vs[nxt][sw1] = vr1;
            __syncthreads();   // writes(kt+1) visible; reads(kt) drained (lgkm)
            if (kt < 30) {     // issue loads for tile kt+2 AFTER the barrier
                int nt = kt + 2;
                kr0 = kg[nt * 512 + tid]; kr1 = kg[nt * 512 + 256 + tid];
                vr0 = vg[vrow0 + nt * 8]; vr1 = vg[vrow1 + nt * 8];
            }
        }
    }

    // epilogue: combine lane-partial l across the two half-lanes, normalize
    float lfull = l_ + __shfl_xor(l_, 32);
    float linv = 1.0f / lfull;
    const int b = bh >> 4, hh = bh & 15;
#pragma unroll
    for (int r = 0; r < 16; ++r) {
        int qrow = (r & 3) + 8 * (r >> 2) + 4 * h;
        float lr = __shfl(linv, qrow);
        int n = q0 + qrow;
        unsigned short* dst = Obuf + ((size_t)(b * 2048 + n)) * 1024 + hh * 64 + li;
        dst[0]  = f2bf(o0[r] * lr);
        dst[32] = f2bf(o1[r] * lr);
    }
}

// ------------------------------- launch ------------------------------------
extern "C" void kernel_launch(void* const* d_in, const int* in_sizes, int n_in,
                              void* d_out, int out_size, void* d_ws, size_t ws_size,
                              hipStream_t stream) {
    const float* x    = (const float*)d_in[0];
    const float* Wqkv = (const float*)d_in[1];
    const float* Wout = (const float*)d_in[2];
    const float* bout = (const float*)d_in[3];
    float* out = (float*)d_out;
    char* ws = (char*)d_ws;

    size_t off = 0;
    unsigned short* xb    = (unsigned short*)(ws + off);
    unsigned short* Obuf  = xb;                                      // alias
    off += (size_t)4096 * 1024 * 2;
    unsigned short* wqkvb = (unsigned short*)(ws + off); off += (size_t)3072 * 1024 * 2;
    unsigned short* woutb = (unsigned short*)(ws + off); off += (size_t)1024 * 1024 * 2;
    float* cosT = (float*)(ws + off); off += (size_t)2048 * 32 * 4;
    float* sinT = (float*)(ws + off); off += (size_t)2048 * 32 * 4;
    unsigned short* Qbuf = (unsigned short*)(ws + off); off += (size_t)32 * 2048 * 64 * 2;
    unsigned short* Kbuf = (unsigned short*)(ws + off); off += (size_t)32 * 2048 * 64 * 2;
    unsigned short* Vt   = (unsigned short*)(ws + off); off += (size_t)32 * 64 * 2048 * 2;

    prepk<<<8448, 256, 0, stream>>>(x, Wqkv, Wout, xb, wqkvb, woutb, cosT, sinT);

    gemm_bt<0, 128><<<dim3(24, 32), 256, 0, stream>>>(
        xb, wqkvb, 4096, 3072, 1024, Qbuf, Kbuf, Vt, cosT, sinT, nullptr, nullptr);

    attnk<<<dim3(16, 32), 256, 0, stream>>>(Qbuf, Kbuf, Vt, Obuf);

    gemm_bt<1, 64><<<dim3(8, 64), 256, 0, stream>>>(
        Obuf, woutb, 4096, 1024, 1024, nullptr, nullptr, nullptr, nullptr, nullptr,
        out, bout);
}